// Round 8
// baseline (1124.044 us; speedup 1.0000x reference)
//
#include <hip/hip_runtime.h>

typedef unsigned short u16;
typedef unsigned int   u32;
typedef __attribute__((ext_vector_type(2)))  u32  u32x2;
typedef __attribute__((ext_vector_type(4)))  float f32x4;
typedef __attribute__((ext_vector_type(16))) float f32x16;
typedef __attribute__((ext_vector_type(8)))  short b16x8;

#define T_ 256
#define B_ 32
#define V_ 32000
#define H_ 256

// fp32 -> bf16 round-to-nearest-even
__device__ __forceinline__ u16 f2bf(float f){
  union { float fv; u32 uv; } v; v.fv = f;
  return (u16)((v.uv + 0x7FFFu + ((v.uv >> 16) & 1u)) >> 16);
}
__device__ __forceinline__ float bf2f(short x){
  union { float fv; u32 uv; } c; c.uv = ((u32)(u16)x) << 16; return c.fv;
}
__device__ __forceinline__ float sigm_fast(float z){
  return __builtin_amdgcn_rcpf(1.0f + __builtin_amdgcn_exp2f(z * -1.44269504f));
}

// ---------------------------------------------------------------------------
// prep: decW -> bf16 ; W^T bf16 copies (WhT0, WiT1, WhT1, WiT0)
// wt[m][j][k] = W_m[k][j]
// ---------------------------------------------------------------------------
__global__ __launch_bounds__(256)
void prep_kernel(const float* __restrict__ Wi, const float* __restrict__ Wh,
                 const float* __restrict__ decW,
                 u16* __restrict__ decWb, u16* __restrict__ wt){
  const int NDEC = V_ * H_;
  const int NWT  = 4 * H_ * H_;
  const int total = NDEC + NWT;
  for (int i = blockIdx.x * blockDim.x + threadIdx.x; i < total;
       i += gridDim.x * blockDim.x){
    if (i < NDEC){
      decWb[i] = f2bf(decW[i]);
    } else {
      int j = i - NDEC;
      int m = j >> 16;
      int r = j & 65535;
      int row = r >> 8;
      int k   = r & 255;
      const float* src = (m == 0) ? Wh
                       : (m == 1) ? (Wi + H_ * H_)
                       : (m == 2) ? (Wh + H_ * H_)
                       :            Wi;
      wt[j] = f2bf(src[k * H_ + row]);
    }
  }
}

// xp layout (matches rec consumer):
//   x[t][batch m][col n] at xp[t*8192 + mt*4096 + (n>>2)*64 + (m&15)*4 + (n&3)]
//   (mt = m>>4; (n>>2)*64 = w*1024 + nt*256 + lh*64)

// ---------------------------------------------------------------------------
// x0: swapped-operand form. Block = one time step t; 4 waves; wave w owns
// cols [w*64, w*64+64) (nt=0..3); mt=0..1 batch halves.
// A = WiT0 fragments (row = output col), B = emb fragments (col = batch row).
// C'[n][m]: thread (lr,lh) holds batch m=lr, cols n = w*64+nt*16+lh*4+rr.
// ---------------------------------------------------------------------------
__global__ __launch_bounds__(256, 2)
void x0_kernel(const int* __restrict__ ids, const float* __restrict__ emb,
               const u16* __restrict__ WiT0, const float* __restrict__ bh,
               float* __restrict__ xp){
  const int tid = threadIdx.x, w = tid >> 6, l = tid & 63;
  const int lr = l & 15, lh = l >> 4;
  const int t = blockIdx.x;

  // weight fragments [nt][ks]
  b16x8 wA[4][8];
  #pragma unroll
  for (int nt = 0; nt < 4; ++nt){
    const int col = w * 64 + nt * 16 + lr;
    #pragma unroll
    for (int ks = 0; ks < 8; ++ks)
      wA[nt][ks] = *(const b16x8*)(WiT0 + (size_t)col * H_ + ks * 32 + lh * 8);
  }

  const int b0 = ids[t * B_ + lr];        // batch row lr (mt=0)
  const int b1 = ids[t * B_ + 16 + lr];   // batch row 16+lr (mt=1)
  const float* er0 = emb + (size_t)b0 * H_;
  const float* er1 = emb + (size_t)b1 * H_;

  f32x4 acc[2][4];
  #pragma unroll
  for (int nt = 0; nt < 4; ++nt){
    f32x4 bs = *(const f32x4*)(bh + w * 64 + nt * 16 + lh * 4);
    acc[0][nt] = bs;
    acc[1][nt] = bs;
  }

  #pragma unroll
  for (int ks = 0; ks < 8; ++ks){
    b16x8 e[2];
    {
      f32x4 a0 = *(const f32x4*)(er0 + ks * 32 + lh * 8);
      f32x4 a1 = *(const f32x4*)(er0 + ks * 32 + lh * 8 + 4);
      f32x4 c0 = *(const f32x4*)(er1 + ks * 32 + lh * 8);
      f32x4 c1 = *(const f32x4*)(er1 + ks * 32 + lh * 8 + 4);
      #pragma unroll
      for (int i2 = 0; i2 < 4; ++i2){
        e[0][i2] = (short)f2bf(a0[i2]); e[0][4 + i2] = (short)f2bf(a1[i2]);
        e[1][i2] = (short)f2bf(c0[i2]); e[1][4 + i2] = (short)f2bf(c1[i2]);
      }
    }
    #pragma unroll
    for (int nt = 0; nt < 4; ++nt){
      acc[0][nt] = __builtin_amdgcn_mfma_f32_16x16x32_bf16(wA[nt][ks], e[0], acc[0][nt], 0, 0, 0);
      acc[1][nt] = __builtin_amdgcn_mfma_f32_16x16x32_bf16(wA[nt][ks], e[1], acc[1][nt], 0, 0, 0);
    }
  }
  #pragma unroll
  for (int mt = 0; mt < 2; ++mt)
    #pragma unroll
    for (int nt = 0; nt < 4; ++nt)
      *(f32x4*)(xp + (size_t)t * 8192 + mt * 4096 + w * 1024 + nt * 256 + lh * 64 + lr * 4)
          = acc[mt][nt];
}

// ---------------------------------------------------------------------------
// fused_rec4: both layers, batch-split (2 blocks x 16 rows), 4 waves (256 thr).
// Swapped-operand MFMA: A = weight frags (row = output col), B = h frags
// (col = batch). Output: thread holds batch=lr, cols lh*4+rr (+nt*16+w*64)
// -> h-writes are packed 8B (1 ds_write_b64 per nt). All 3 weight matrices
// persistent (384 regs, 1 wave/SIMD, unified VGPR/AGPR file).
// Skewed schedule (round-6/7-verified): step s -> h0[s], h1[s-1]; 1 barrier.
//   h0[u] in h0b[(u+1)&1]; h1[u] in h1b[(u+1)&1].
// LDS: byte(row,col) = row*512 + ((col*2) ^ ((row&7)<<4))
// ---------------------------------------------------------------------------
__global__ __launch_bounds__(256, 1)
void fused_rec4(const u16* __restrict__ wt, const float* __restrict__ xp,
                const float* __restrict__ bh,
                u16* __restrict__ outseq, float* __restrict__ hid){
  __shared__ u16 h0b[2][16 * H_];                    // 2 x 8 KiB
  __shared__ u16 h1b[2][16 * H_];                    // 2 x 8 KiB
  const int tid = threadIdx.x, w = tid >> 6, l = tid & 63;
  const int lr = l & 15, lh = l >> 4;
  const int bid = blockIdx.x;

  const u16* whT0 = wt;
  const u16* wiT1 = wt + 65536;
  const u16* whT1 = wt + 131072;

  // persistent weight fragments [nt][ks] (A-role: row = output col)
  b16x8 wH0[4][8], wI1[4][8], wH1[4][8];
  #pragma unroll
  for (int nt = 0; nt < 4; ++nt){
    const int col = w * 64 + nt * 16 + lr;
    #pragma unroll
    for (int ks = 0; ks < 8; ++ks){
      wH0[nt][ks] = *(const b16x8*)(whT0 + (size_t)col * H_ + ks * 32 + lh * 8);
      wI1[nt][ks] = *(const b16x8*)(wiT1 + (size_t)col * H_ + ks * 32 + lh * 8);
      wH1[nt][ks] = *(const b16x8*)(whT1 + (size_t)col * H_ + ks * 32 + lh * 8);
    }
  }
  // layer-1 bias vectors (per nt, 4 cols lh*4+rr)
  f32x4 bs1[4];
  #pragma unroll
  for (int nt = 0; nt < 4; ++nt)
    bs1[nt] = *(const f32x4*)(bh + H_ + w * 64 + nt * 16 + lh * 4);

  // B-fragment read offsets (row = lr, k = ks*32 + lh*8)
  int ra[8];
  #pragma unroll
  for (int ks = 0; ks < 8; ++ks)
    ra[ks] = lr * 512 + ((ks * 64 + lh * 16) ^ ((lr & 7) << 4));

  // packed h-write byte addrs (row = lr, col = w*64+nt*16+lh*4, 8 B)
  int wrh[4];
  #pragma unroll
  for (int nt = 0; nt < 4; ++nt)
    wrh[nt] = lr * 512 + ((w * 128 + nt * 32 + lh * 8) ^ ((lr & 7) << 4));

  // linear store-read (32 B/thread): row = tid>>4
  const int srow = tid >> 4, scolb = (tid & 15) * 32;
  const int sa0 = srow * 512 + (scolb ^ ((srow & 7) << 4));
  const int sa1 = srow * 512 + ((scolb + 16) ^ ((srow & 7) << 4));
  const size_t sgbase = (size_t)(bid * 16 + srow) * H_ + (tid & 15) * 16;

  const int xoff = bid * 4096 + w * 1024 + lh * 64 + lr * 4;

  // zero h0[-1] (h0b[0]) and h1[-1] (h1b[0])
  { u32* z0 = (u32*)h0b[0];
    for (int i = tid; i < 2048; i += 256) z0[i] = 0;
    u32* z1 = (u32*)h1b[0];
    for (int i = tid; i < 2048; i += 256) z1[i] = 0; }
  __syncthreads();

#define PACKW(DST, ADDR, V0, V1, V2, V3)                                        \
  { u32x2 pk;                                                                   \
    pk[0] = (u32)f2bf(V0) | ((u32)f2bf(V1) << 16);                              \
    pk[1] = (u32)f2bf(V2) | ((u32)f2bf(V3) << 16);                              \
    *(u32x2*)((DST) + (ADDR)) = pk; }

#define STEP(PAR, S)                                                            \
  {                                                                             \
    const char* rb0 = (const char*)h0b[PAR];                                    \
    const char* rb1 = (const char*)h1b[1 - (PAR)];                              \
    /* x for this step (consumed ~64 MFMAs later) */                            \
    f32x4 xv[4];                                                                \
    _Pragma("unroll")                                                           \
    for (int nt = 0; nt < 4; ++nt)                                              \
      xv[nt] = *(const f32x4*)(xp + (size_t)(S) * 8192 + xoff + nt * 256);      \
    /* outseq store lag-2 (reads rb1; nobody writes rb1 this step) */           \
    if ((S) >= 2){                                                              \
      b16x8 v0 = *(const b16x8*)(rb1 + sa0);                                    \
      b16x8 v1 = *(const b16x8*)(rb1 + sa1);                                    \
      u16* hs = outseq + (size_t)((S) - 2) * 8192 + sgbase;                     \
      *(b16x8*)(hs)     = v0;                                                   \
      *(b16x8*)(hs + 8) = v1;                                                   \
    }                                                                           \
    f32x4 c[4], d[4];                                                           \
    _Pragma("unroll")                                                           \
    for (int nt = 0; nt < 4; ++nt){ c[nt] = (f32x4){}; d[nt] = bs1[nt]; }       \
    _Pragma("unroll")                                                           \
    for (int ks = 0; ks < 8; ++ks){                                             \
      b16x8 a = *(const b16x8*)(rb0 + ra[ks]);                                  \
      _Pragma("unroll")                                                         \
      for (int nt = 0; nt < 4; ++nt){                                           \
        c[nt] = __builtin_amdgcn_mfma_f32_16x16x32_bf16(wH0[nt][ks], a, c[nt], 0, 0, 0); \
        d[nt] = __builtin_amdgcn_mfma_f32_16x16x32_bf16(wI1[nt][ks], a, d[nt], 0, 0, 0); \
      }                                                                         \
    }                                                                           \
    { char* wb0 = (char*)h0b[1 - (PAR)];                                        \
      _Pragma("unroll")                                                         \
      for (int nt = 0; nt < 4; ++nt)                                            \
        PACKW(wb0, wrh[nt], sigm_fast(c[nt][0] + xv[nt][0]),                    \
                            sigm_fast(c[nt][1] + xv[nt][1]),                    \
                            sigm_fast(c[nt][2] + xv[nt][2]),                    \
                            sigm_fast(c[nt][3] + xv[nt][3]))                    \
    }                                                                           \
    _Pragma("unroll")                                                           \
    for (int ks = 0; ks < 8; ++ks){                                             \
      b16x8 a = *(const b16x8*)(rb1 + ra[ks]);                                  \
      _Pragma("unroll")                                                         \
      for (int nt = 0; nt < 4; ++nt)                                            \
        d[nt] = __builtin_amdgcn_mfma_f32_16x16x32_bf16(wH1[nt][ks], a, d[nt], 0, 0, 0); \
    }                                                                           \
    if ((S) >= 1){                                                              \
      char* wb1 = (char*)h1b[PAR];                                              \
      _Pragma("unroll")                                                         \
      for (int nt = 0; nt < 4; ++nt)                                            \
        PACKW(wb1, wrh[nt], sigm_fast(d[nt][0]), sigm_fast(d[nt][1]),           \
                            sigm_fast(d[nt][2]), sigm_fast(d[nt][3]))           \
    }                                                                           \
    __syncthreads();                                                            \
  }

  for (int s2 = 0; s2 < 128; ++s2){
    const int s = s2 * 2;
    STEP(0, s)
    STEP(1, s + 1)
  }
#undef STEP

  // epilogue: h0[255] in h0b[0]; h1[254] in h1b[1]; compute h1[255]
  {
    const char* rb0 = (const char*)h0b[0];
    const char* rb1 = (const char*)h1b[1];
    { b16x8 v0 = *(const b16x8*)(rb1 + sa0);
      b16x8 v1 = *(const b16x8*)(rb1 + sa1);
      u16* hs = outseq + (size_t)254 * 8192 + sgbase;
      *(b16x8*)(hs)     = v0;
      *(b16x8*)(hs + 8) = v1; }

    f32x4 d[4];
    #pragma unroll
    for (int nt = 0; nt < 4; ++nt) d[nt] = bs1[nt];
    #pragma unroll
    for (int ks = 0; ks < 8; ++ks){
      b16x8 a0 = *(const b16x8*)(rb0 + ra[ks]);
      b16x8 a1 = *(const b16x8*)(rb1 + ra[ks]);
      #pragma unroll
      for (int nt = 0; nt < 4; ++nt){
        d[nt] = __builtin_amdgcn_mfma_f32_16x16x32_bf16(wI1[nt][ks], a0, d[nt], 0, 0, 0);
        d[nt] = __builtin_amdgcn_mfma_f32_16x16x32_bf16(wH1[nt][ks], a1, d[nt], 0, 0, 0);
      }
    }
    { char* wb1 = (char*)h1b[0];
      #pragma unroll
      for (int nt = 0; nt < 4; ++nt)
        PACKW(wb1, wrh[nt], sigm_fast(d[nt][0]), sigm_fast(d[nt][1]),
                            sigm_fast(d[nt][2]), sigm_fast(d[nt][3]))
    }
    __syncthreads();

    b16x8 h0v0 = *(const b16x8*)((const char*)h0b[0] + sa0);
    b16x8 h0v1 = *(const b16x8*)((const char*)h0b[0] + sa1);
    b16x8 h1v0 = *(const b16x8*)((const char*)h1b[0] + sa0);
    b16x8 h1v1 = *(const b16x8*)((const char*)h1b[0] + sa1);
    u16* hs2 = outseq + (size_t)255 * 8192 + sgbase;
    *(b16x8*)(hs2)     = h1v0;
    *(b16x8*)(hs2 + 8) = h1v1;
    float* hd0 = hid + sgbase;
    float* hd1 = hid + 8192 + sgbase;
    #pragma unroll
    for (int j = 0; j < 8; ++j){
      hd0[j]     = bf2f(h0v0[j]);
      hd0[8 + j] = bf2f(h0v1[j]);
      hd1[j]     = bf2f(h1v0[j]);
      hd1[8 + j] = bf2f(h1v1[j]);
    }
  }
#undef PACKW
}

// ---------------------------------------------------------------------------
// decoder: decoded[8192][32000] = outseq @ decW^T + decB   (unchanged)
// ---------------------------------------------------------------------------
__global__ __launch_bounds__(512, 1)
void dec_kernel(const u16* __restrict__ A, const u16* __restrict__ Bw,
                const float* __restrict__ decB, float* __restrict__ out){
  __shared__ u16 sA[2][256 * 64];
  __shared__ u16 sB[2][256 * 64];
  const int tid = threadIdx.x, w = tid >> 6, l = tid & 63;
  const int la = l & 31, hi = l >> 5;
  const int wm = w >> 2, wn = w & 3;

  const int bid = blockIdx.x;
  const int sb  = (bid & 7) * 500 + (bid >> 3);
  const int mb  = sb & 31;
  const int nb  = sb >> 5;

  const int srow = tid >> 3;
  const int sc   = tid & 7;
  const int scx  = sc ^ (srow & 7);
  const size_t gA = ((size_t)(mb * 256 + srow)) * H_ + sc * 8;
  const size_t gB = ((size_t)(nb * 256 + srow)) * H_ + sc * 8;
  const int    sl = srow * 128 + scx * 16;

  b16x8 rA[4], rB[4];
#define GLOADS(KK)                                                              \
  { _Pragma("unroll")                                                           \
    for (int s = 0; s < 4; ++s){                                                \
      rA[s] = *(const b16x8*)(A  + gA + (size_t)s * 64 * H_ + (KK) * 64);       \
      rB[s] = *(const b16x8*)(Bw + gB + (size_t)s * 64 * H_ + (KK) * 64);       \
    } }
#define DSWRITE(BUF)                                                            \
  { _Pragma("unroll")                                                           \
    for (int s = 0; s < 4; ++s){                                                \
      *(b16x8*)((char*)sA[BUF] + s * 8192 + sl) = rA[s];                        \
      *(b16x8*)((char*)sB[BUF] + s * 8192 + sl) = rB[s];                        \
    } }

  const int aRow = wm * 128 + la;
  const int bRow = wn * 64 + la;
  int fOff[4];
  #pragma unroll
  for (int ks = 0; ks < 4; ++ks)
    fOff[ks] = ((ks * 32 + hi * 16) ^ ((la & 7) << 4));

  f32x16 acc[4][2];
  #pragma unroll
  for (int mt = 0; mt < 4; ++mt)
    #pragma unroll
    for (int nt = 0; nt < 2; ++nt)
      acc[mt][nt] = (f32x16){};

  GLOADS(0);
  #pragma unroll
  for (int kk = 0; kk < 4; ++kk){
    DSWRITE(kk & 1);
    if (kk < 3) GLOADS(kk + 1);
    __syncthreads();
    const char* bufA = (const char*)sA[kk & 1];
    const char* bufB = (const char*)sB[kk & 1];
    #pragma unroll
    for (int ks = 0; ks < 4; ++ks){
      b16x8 aF[4], bF[2];
      #pragma unroll
      for (int mt = 0; mt < 4; ++mt)
        aF[mt] = *(const b16x8*)(bufA + (aRow + mt * 32) * 128 + fOff[ks]);
      #pragma unroll
      for (int nt = 0; nt < 2; ++nt)
        bF[nt] = *(const b16x8*)(bufB + (bRow + nt * 32) * 128 + fOff[ks]);
      #pragma unroll
      for (int mt = 0; mt < 4; ++mt)
        #pragma unroll
        for (int nt = 0; nt < 2; ++nt)
          acc[mt][nt] = __builtin_amdgcn_mfma_f32_32x32x16_bf16(aF[mt], bF[nt], acc[mt][nt], 0, 0, 0);
    }
    __syncthreads();
  }
#undef GLOADS
#undef DSWRITE

  #pragma unroll
  for (int nt = 0; nt < 2; ++nt){
    const int colg = nb * 256 + wn * 64 + nt * 32 + la;
    const float bias = decB[colg];
    #pragma unroll
    for (int mt = 0; mt < 4; ++mt){
      const int rowb = mb * 256 + wm * 128 + mt * 32 + hi * 4;
      #pragma unroll
      for (int r = 0; r < 16; ++r){
        const int rowg = rowb + (r & 3) + 8 * (r >> 2);
        out[(size_t)rowg * V_ + colg] = acc[mt][nt][r] + bias;
      }
    }
  }
}

// ---------------------------------------------------------------------------
extern "C" void kernel_launch(void* const* d_in, const int* in_sizes, int n_in,
                              void* d_out, int out_size, void* d_ws, size_t ws_size,
                              hipStream_t stream){
  const int*   ids  = (const int*)  d_in[0];
  const float* emb  = (const float*)d_in[1];
  const float* Wi   = (const float*)d_in[2];
  const float* Wh   = (const float*)d_in[3];
  const float* bh   = (const float*)d_in[4];
  const float* decW = (const float*)d_in[5];
  const float* decB = (const float*)d_in[6];
  float* out = (float*)d_out;

  char* ws = (char*)d_ws;
  u16*  decWb  = (u16*)(ws);                       // 16,384,000 B
  u16*  wt     = (u16*)(ws + 16384000);            //    524,288 B
  u16*  outseq = (u16*)(ws + 16908288);            //  4,194,304 B
  float* xp    = (float*)(ws + 21102592);          //  8,388,608 B

  float* hid = out + (size_t)T_ * B_ * V_;         // [L][B][H] fp32 tail of d_out

  prep_kernel<<<2048, 256, 0, stream>>>(Wi, Wh, decW, decWb, wt);
  x0_kernel<<<256, 256, 0, stream>>>(ids, emb, wt + 3 * H_ * H_, bh, xp);
  fused_rec4<<<2, 256, 0, stream>>>(wt, xp, bh, outseq, hid);
  dec_kernel<<<4000, 512, 0, stream>>>(outseq, decWb, decB, out);
}

// Round 9
// 761.224 us; speedup vs baseline: 1.4766x; 1.4766x over previous
//
#include <hip/hip_runtime.h>

typedef unsigned short u16;
typedef unsigned int   u32;
typedef __attribute__((ext_vector_type(4)))  float f32x4;
typedef __attribute__((ext_vector_type(16))) float f32x16;
typedef __attribute__((ext_vector_type(8)))  short b16x8;

#define T_ 256
#define B_ 32
#define V_ 32000
#define H_ 256

// fp32 -> bf16 round-to-nearest-even
__device__ __forceinline__ u16 f2bf(float f){
  union { float fv; u32 uv; } v; v.fv = f;
  return (u16)((v.uv + 0x7FFFu + ((v.uv >> 16) & 1u)) >> 16);
}
__device__ __forceinline__ float bf2f(short x){
  union { float fv; u32 uv; } c; c.uv = ((u32)(u16)x) << 16; return c.fv;
}
__device__ __forceinline__ float sigm_fast(float z){
  return __builtin_amdgcn_rcpf(1.0f + __builtin_amdgcn_exp2f(z * -1.44269504f));
}

// ---------------------------------------------------------------------------
// prep: decW -> bf16 ; W^T bf16 copies (WhT0, WiT1, WhT1, WiT0)
// wt[m][j][k] = W_m[k][j]
// ---------------------------------------------------------------------------
__global__ __launch_bounds__(256)
void prep_kernel(const float* __restrict__ Wi, const float* __restrict__ Wh,
                 const float* __restrict__ decW,
                 u16* __restrict__ decWb, u16* __restrict__ wt){
  const int NDEC = V_ * H_;
  const int NWT  = 4 * H_ * H_;
  const int total = NDEC + NWT;
  for (int i = blockIdx.x * blockDim.x + threadIdx.x; i < total;
       i += gridDim.x * blockDim.x){
    if (i < NDEC){
      decWb[i] = f2bf(decW[i]);
    } else {
      int j = i - NDEC;
      int m = j >> 16;
      int r = j & 65535;
      int row = r >> 8;
      int k   = r & 255;
      const float* src = (m == 0) ? Wh
                       : (m == 1) ? (Wi + H_ * H_)
                       : (m == 2) ? (Wh + H_ * H_)
                       :            Wi;
      wt[j] = f2bf(src[k * H_ + row]);
    }
  }
}

// xp permuted layout for the 16-row M=16 consumer (round-7 verified):
//   x[t][bid*16 + lh*4 + rr][col]  ->  xp[t*8192 + bid*4096 + lh*1024 + col*4 + rr]

// ---------------------------------------------------------------------------
// x0[t][b][j] = bh0[j] + emb[ids[t,b]] @ Wi0   (permuted store) — round-7
// ---------------------------------------------------------------------------
__global__ __launch_bounds__(512, 2)
void x0_kernel(const int* __restrict__ ids, const float* __restrict__ emb,
               const u16* __restrict__ WiT0, const float* __restrict__ bh,
               float* __restrict__ xp){
  const int tid = threadIdx.x, w = tid >> 6, l = tid & 63, lr = l & 15, lh = l >> 4;
  const int mb = blockIdx.x >> 2;
  const int nb = blockIdx.x & 3;
  const int arow = mb * 128 + w * 16 + lr;
  const int id = ids[arow];
  const float* erow = emb + (size_t)id * H_;

  f32x4 acc[4];
  #pragma unroll
  for (int nt = 0; nt < 4; ++nt){
    float b0 = bh[nb * 64 + nt * 16 + lr];
    acc[nt] = (f32x4){b0, b0, b0, b0};
  }
  #pragma unroll
  for (int ks = 0; ks < 8; ++ks){
    const float* ap = erow + ks * 32 + lh * 8;
    f32x4 e0 = *(const f32x4*)(ap);
    f32x4 e1 = *(const f32x4*)(ap + 4);
    b16x8 a;
    #pragma unroll
    for (int i2 = 0; i2 < 4; ++i2){
      a[i2]     = (short)f2bf(e0[i2]);
      a[4 + i2] = (short)f2bf(e1[i2]);
    }
    #pragma unroll
    for (int nt = 0; nt < 4; ++nt){
      b16x8 b = *(const b16x8*)(WiT0 + (size_t)(nb * 64 + nt * 16 + lr) * H_ + ks * 32 + lh * 8);
      acc[nt] = __builtin_amdgcn_mfma_f32_16x16x32_bf16(a, b, acc[nt], 0, 0, 0);
    }
  }
  // row gr = mb*128 + w*16 + lh*4 + rr  ->  t = gr>>5, b = (w&1)*16 + lh*4 + rr
  const int t    = mb * 4 + (w >> 1);
  const int bid2 = w & 1;
  #pragma unroll
  for (int nt = 0; nt < 4; ++nt){
    const int col = nb * 64 + nt * 16 + lr;
    *(f32x4*)(xp + (size_t)t * 8192 + bid2 * 4096 + lh * 1024 + col * 4) = acc[nt];
  }
}

// ---------------------------------------------------------------------------
// fused_rec16 (round-7 verified, 347 us): both layers, batch-split.
// Block bid owns rows [bid*16, +16). 8 waves, 16x16x32 MFMA; wave w owns
// cols [w*32, +32). All weights persistent. Skewed schedule, 1 barrier/step.
//   h0[u] in h0b[(u+1)&1]; h1[u] in h1b[(u+1)&1].
// LDS tile 16x256 bf16: byte(row,col) = row*512 + ((col*2) ^ ((row&7)<<4))
// ---------------------------------------------------------------------------
__global__ __launch_bounds__(512, 1)
void fused_rec16(const u16* __restrict__ wt, const float* __restrict__ xp,
                 const float* __restrict__ bh,
                 u16* __restrict__ outseq, float* __restrict__ hid){
  __shared__ u16 h0b[2][16 * H_];                    // 2 x 8 KiB
  __shared__ u16 h1b[2][16 * H_];                    // 2 x 8 KiB
  const int tid = threadIdx.x, w = tid >> 6, l = tid & 63;
  const int lr = l & 15, lh = l >> 4;
  const int bid = blockIdx.x;

  const u16* whT0 = wt;
  const u16* wiT1 = wt + 65536;
  const u16* whT1 = wt + 131072;

  b16x8 wH0[2][8], wI1[2][8], wH1[2][8];
  #pragma unroll
  for (int nt = 0; nt < 2; ++nt){
    const int col = w * 32 + nt * 16 + lr;
    #pragma unroll
    for (int ks = 0; ks < 8; ++ks){
      wH0[nt][ks] = *(const b16x8*)(whT0 + (size_t)col * H_ + ks * 32 + lh * 8);
      wI1[nt][ks] = *(const b16x8*)(wiT1 + (size_t)col * H_ + ks * 32 + lh * 8);
      wH1[nt][ks] = *(const b16x8*)(whT1 + (size_t)col * H_ + ks * 32 + lh * 8);
    }
  }
  const float b1a = bh[H_ + w * 32 + lr];
  const float b1b = bh[H_ + w * 32 + 16 + lr];

  int ra[8];
  #pragma unroll
  for (int ks = 0; ks < 8; ++ks)
    ra[ks] = lr * 512 + ((ks * 64 + lh * 16) ^ ((lr & 7) << 4));

  int wa[2][4];
  #pragma unroll
  for (int nt = 0; nt < 2; ++nt)
    #pragma unroll
    for (int rr = 0; rr < 4; ++rr){
      const int row = lh * 4 + rr;
      wa[nt][rr] = row * 512 + (((w * 32 + nt * 16 + lr) * 2) ^ ((row & 7) << 4));
    }

  const int srow = tid >> 5, scolb = (tid & 31) * 16;
  const int sa = srow * 512 + (scolb ^ ((srow & 7) << 4));
  const size_t sgbase = (size_t)(bid * 16 + srow) * H_ + (tid & 31) * 8;

  const int xoff = bid * 4096 + lh * 1024 + (w * 32 + lr) * 4;

  { u32* z0 = (u32*)h0b[0];
    for (int i = tid; i < 2048; i += 512) z0[i] = 0;
    u32* z1 = (u32*)h1b;
    for (int i = tid; i < 4096; i += 512) z1[i] = 0; }

  f32x4 xc0, xc1, xn0, xn1;
  xc0 = *(const f32x4*)(xp + xoff);
  xc1 = *(const f32x4*)(xp + xoff + 64);
  __syncthreads();

#define STEP(PAR, S)                                                            \
  {                                                                             \
    const char* rb0 = (const char*)h0b[PAR];                                    \
    const char* rb1 = (const char*)h1b[1 - (PAR)];                              \
    if ((S) >= 2){                                                              \
      b16x8 v = *(const b16x8*)(rb1 + sa);                                      \
      *(b16x8*)(outseq + (size_t)((S) - 2) * 8192 + sgbase) = v;                \
    }                                                                           \
    f32x4 c0 = xc0, c1 = xc1;                                                   \
    f32x4 d0 = (f32x4){b1a, b1a, b1a, b1a};                                     \
    f32x4 d1 = (f32x4){b1b, b1b, b1b, b1b};                                     \
    _Pragma("unroll")                                                           \
    for (int ks = 0; ks < 8; ++ks){                                             \
      b16x8 a = *(const b16x8*)(rb0 + ra[ks]);                                  \
      c0 = __builtin_amdgcn_mfma_f32_16x16x32_bf16(a, wH0[0][ks], c0, 0, 0, 0); \
      c1 = __builtin_amdgcn_mfma_f32_16x16x32_bf16(a, wH0[1][ks], c1, 0, 0, 0); \
      d0 = __builtin_amdgcn_mfma_f32_16x16x32_bf16(a, wI1[0][ks], d0, 0, 0, 0); \
      d1 = __builtin_amdgcn_mfma_f32_16x16x32_bf16(a, wI1[1][ks], d1, 0, 0, 0); \
    }                                                                           \
    { const float* pn = xp + (size_t)(((S) < 255) ? (S) + 1 : 255) * 8192 + xoff; \
      xn0 = *(const f32x4*)(pn);                                                \
      xn1 = *(const f32x4*)(pn + 64); }                                         \
    { char* wb0 = (char*)h0b[1 - (PAR)];                                        \
      _Pragma("unroll")                                                         \
      for (int rr = 0; rr < 4; ++rr){                                           \
        *(u16*)(wb0 + wa[0][rr]) = f2bf(sigm_fast(c0[rr]));                     \
        *(u16*)(wb0 + wa[1][rr]) = f2bf(sigm_fast(c1[rr]));                     \
      }                                                                         \
    }                                                                           \
    if ((S) >= 1){                                                              \
      _Pragma("unroll")                                                         \
      for (int ks = 0; ks < 8; ++ks){                                           \
        b16x8 a = *(const b16x8*)(rb1 + ra[ks]);                                \
        d0 = __builtin_amdgcn_mfma_f32_16x16x32_bf16(a, wH1[0][ks], d0, 0, 0, 0); \
        d1 = __builtin_amdgcn_mfma_f32_16x16x32_bf16(a, wH1[1][ks], d1, 0, 0, 0); \
      }                                                                         \
      char* wb1 = (char*)h1b[PAR];                                              \
      _Pragma("unroll")                                                         \
      for (int rr = 0; rr < 4; ++rr){                                           \
        *(u16*)(wb1 + wa[0][rr]) = f2bf(sigm_fast(d0[rr]));                     \
        *(u16*)(wb1 + wa[1][rr]) = f2bf(sigm_fast(d1[rr]));                     \
      }                                                                         \
    }                                                                           \
    xc0 = xn0; xc1 = xn1;                                                       \
    __syncthreads();                                                            \
  }

  for (int s2 = 0; s2 < 128; ++s2){
    const int s = s2 * 2;
    STEP(0, s)
    STEP(1, s + 1)
  }
#undef STEP

  // epilogue: h0[255] in h0b[0]; h1[254] in h1b[1]; compute h1[255]
  {
    const char* rb0 = (const char*)h0b[0];
    const char* rb1 = (const char*)h1b[1];
    { b16x8 v = *(const b16x8*)(rb1 + sa);
      *(b16x8*)(outseq + (size_t)254 * 8192 + sgbase) = v; }

    f32x4 d0 = (f32x4){b1a, b1a, b1a, b1a};
    f32x4 d1 = (f32x4){b1b, b1b, b1b, b1b};
    #pragma unroll
    for (int ks = 0; ks < 8; ++ks){
      b16x8 a  = *(const b16x8*)(rb0 + ra[ks]);
      b16x8 a2 = *(const b16x8*)(rb1 + ra[ks]);
      d0 = __builtin_amdgcn_mfma_f32_16x16x32_bf16(a,  wI1[0][ks], d0, 0, 0, 0);
      d1 = __builtin_amdgcn_mfma_f32_16x16x32_bf16(a,  wI1[1][ks], d1, 0, 0, 0);
      d0 = __builtin_amdgcn_mfma_f32_16x16x32_bf16(a2, wH1[0][ks], d0, 0, 0, 0);
      d1 = __builtin_amdgcn_mfma_f32_16x16x32_bf16(a2, wH1[1][ks], d1, 0, 0, 0);
    }
    char* wb1 = (char*)h1b[0];
    #pragma unroll
    for (int rr = 0; rr < 4; ++rr){
      *(u16*)(wb1 + wa[0][rr]) = f2bf(sigm_fast(d0[rr]));
      *(u16*)(wb1 + wa[1][rr]) = f2bf(sigm_fast(d1[rr]));
    }
    __syncthreads();

    b16x8 h1v = *(const b16x8*)((const char*)h1b[0] + sa);
    b16x8 h0v = *(const b16x8*)((const char*)h0b[0] + sa);
    *(b16x8*)(outseq + (size_t)255 * 8192 + sgbase) = h1v;
    float* hd0 = hid + sgbase;
    float* hd1 = hid + 8192 + sgbase;
    #pragma unroll
    for (int j = 0; j < 8; ++j){
      hd0[j] = bf2f(h0v[j]);
      hd1[j] = bf2f(h1v[j]);
    }
  }
}

// ---------------------------------------------------------------------------
// decoder: decoded[8192][32000] = outseq @ decW^T + decB
// NEW: 256x128 tile, BK=32 double-buffer (48 KiB LDS), 8 waves
// (wm=0..1 x 128 rows, wn=0..3 x 32 cols), target 2 blocks/CU.
// LDS row stride 64 B, chunk swizzle: chunk ^= row&3 (both sides).
// Grid 8000 = 8 XCDs x 1000 (bijective chunked swizzle).
// ---------------------------------------------------------------------------
__global__ __launch_bounds__(512, 4)
void dec_kernel(const u16* __restrict__ A, const u16* __restrict__ Bw,
                const float* __restrict__ decB, float* __restrict__ out){
  __shared__ u16 sA[2][256 * 32];                   // 2 x 16 KiB
  __shared__ u16 sB[2][128 * 32];                   // 2 x 8 KiB
  const int tid = threadIdx.x, w = tid >> 6, l = tid & 63;
  const int la = l & 31, hi = l >> 5;
  const int wm = w >> 2, wn = w & 3;

  // XCD-chunked swizzle: 8000 blocks = 8 x 1000
  const int bid = blockIdx.x;
  const int sb  = (bid & 7) * 1000 + (bid >> 3);
  const int mb  = sb & 31;                          // 0..31  (256-row block)
  const int nb  = sb >> 5;                          // 0..249 (128-col block)

  // staging: srow 0..127, chunk sc 0..3 (8 bf16 = 16 B)
  const int srow = tid >> 2;
  const int sc   = tid & 3;
  const int scx  = sc ^ (srow & 3);
  const size_t gA = ((size_t)(mb * 256 + srow)) * H_ + sc * 8;
  const size_t gB = ((size_t)(nb * 128 + srow)) * H_ + sc * 8;
  const int    sl = srow * 64 + scx * 16;

  b16x8 rA[2], rB;
#define GLOADS(KK)                                                              \
  { rA[0] = *(const b16x8*)(A  + gA + (KK) * 32);                               \
    rA[1] = *(const b16x8*)(A  + gA + (size_t)128 * H_ + (KK) * 32);            \
    rB    = *(const b16x8*)(Bw + gB + (KK) * 32); }
#define DSWRITE(BUF)                                                            \
  { *(b16x8*)((char*)sA[BUF] + sl)        = rA[0];                              \
    *(b16x8*)((char*)sA[BUF] + 8192 + sl) = rA[1];                              \
    *(b16x8*)((char*)sB[BUF] + sl)        = rB; }

  // fragment read offsets, row stride 64 B
  const int aRow = wm * 128 + la;                   // + mt*32
  const int bRow = wn * 32 + la;
  int fOff[2];
  #pragma unroll
  for (int ks = 0; ks < 2; ++ks)
    fOff[ks] = ((ks * 32 + hi * 16) ^ ((la & 3) << 4));

  f32x16 acc[4];
  #pragma unroll
  for (int mt = 0; mt < 4; ++mt)
    acc[mt] = (f32x16){};

  GLOADS(0);
  #pragma unroll
  for (int kk = 0; kk < 8; ++kk){
    DSWRITE(kk & 1);
    if (kk < 7) GLOADS(kk + 1);
    __syncthreads();
    const char* bufA = (const char*)sA[kk & 1];
    const char* bufB = (const char*)sB[kk & 1];
    #pragma unroll
    for (int ks = 0; ks < 2; ++ks){
      b16x8 bF = *(const b16x8*)(bufB + bRow * 64 + fOff[ks]);
      #pragma unroll
      for (int mt = 0; mt < 4; ++mt){
        b16x8 aF = *(const b16x8*)(bufA + (aRow + mt * 32) * 64 + fOff[ks]);
        acc[mt] = __builtin_amdgcn_mfma_f32_32x32x16_bf16(aF, bF, acc[mt], 0, 0, 0);
      }
    }
    __syncthreads();
  }
#undef GLOADS
#undef DSWRITE

  // epilogue: bias + store (C layout: col=la, row=(r&3)+8*(r>>2)+4*hi)
  const int colg = nb * 128 + wn * 32 + la;
  const float bias = decB[colg];
  #pragma unroll
  for (int mt = 0; mt < 4; ++mt){
    const int rowb = mb * 256 + wm * 128 + mt * 32 + hi * 4;
    #pragma unroll
    for (int r = 0; r < 16; ++r){
      const int rowg = rowb + (r & 3) + 8 * (r >> 2);
      out[(size_t)rowg * V_ + colg] = acc[mt][r] + bias;
    }
  }
}

// ---------------------------------------------------------------------------
extern "C" void kernel_launch(void* const* d_in, const int* in_sizes, int n_in,
                              void* d_out, int out_size, void* d_ws, size_t ws_size,
                              hipStream_t stream){
  const int*   ids  = (const int*)  d_in[0];
  const float* emb  = (const float*)d_in[1];
  const float* Wi   = (const float*)d_in[2];
  const float* Wh   = (const float*)d_in[3];
  const float* bh   = (const float*)d_in[4];
  const float* decW = (const float*)d_in[5];
  const float* decB = (const float*)d_in[6];
  float* out = (float*)d_out;

  char* ws = (char*)d_ws;
  u16*  decWb  = (u16*)(ws);                       // 16,384,000 B
  u16*  wt     = (u16*)(ws + 16384000);            //    524,288 B
  u16*  outseq = (u16*)(ws + 16908288);            //  4,194,304 B
  float* xp    = (float*)(ws + 21102592);          //  8,388,608 B

  float* hid = out + (size_t)T_ * B_ * V_;         // [L][B][H] fp32 tail of d_out

  prep_kernel<<<2048, 256, 0, stream>>>(Wi, Wh, decW, decWb, wt);
  x0_kernel<<<256, 512, 0, stream>>>(ids, emb, wt + 3 * H_ * H_, bh, xp);
  fused_rec16<<<2, 512, 0, stream>>>(wt, xp, bh, outseq, hid);
  dec_kernel<<<8000, 512, 0, stream>>>(outseq, decWb, decB, out);
}

// Round 10
// 618.620 us; speedup vs baseline: 1.8170x; 1.2305x over previous
//
#include <hip/hip_runtime.h>

typedef unsigned short u16;
typedef unsigned int   u32;
typedef __attribute__((ext_vector_type(2)))  u32  u32x2;
typedef __attribute__((ext_vector_type(4)))  float f32x4;
typedef __attribute__((ext_vector_type(16))) float f32x16;
typedef __attribute__((ext_vector_type(8)))  short b16x8;

#define T_ 256
#define B_ 32
#define V_ 32000
#define H_ 256

// fp32 -> bf16 round-to-nearest-even
__device__ __forceinline__ u16 f2bf(float f){
  union { float fv; u32 uv; } v; v.fv = f;
  return (u16)((v.uv + 0x7FFFu + ((v.uv >> 16) & 1u)) >> 16);
}
__device__ __forceinline__ float bf2f(short x){
  union { float fv; u32 uv; } c; c.uv = ((u32)(u16)x) << 16; return c.fv;
}
__device__ __forceinline__ float sigm_fast(float z){
  return __builtin_amdgcn_rcpf(1.0f + __builtin_amdgcn_exp2f(z * -1.44269504f));
}

// ---------------------------------------------------------------------------
// prep: decW -> bf16 ; W^T bf16 copies (WhT0, WiT1, WhT1, WiT0)
// wt[m][j][k] = W_m[k][j]
// ---------------------------------------------------------------------------
__global__ __launch_bounds__(256)
void prep_kernel(const float* __restrict__ Wi, const float* __restrict__ Wh,
                 const float* __restrict__ decW,
                 u16* __restrict__ decWb, u16* __restrict__ wt){
  const int NDEC = V_ * H_;
  const int NWT  = 4 * H_ * H_;
  const int total = NDEC + NWT;
  for (int i = blockIdx.x * blockDim.x + threadIdx.x; i < total;
       i += gridDim.x * blockDim.x){
    if (i < NDEC){
      decWb[i] = f2bf(decW[i]);
    } else {
      int j = i - NDEC;
      int m = j >> 16;
      int r = j & 65535;
      int row = r >> 8;
      int k   = r & 255;
      const float* src = (m == 0) ? Wh
                       : (m == 1) ? (Wi + H_ * H_)
                       : (m == 2) ? (Wh + H_ * H_)
                       :            Wi;
      wt[j] = f2bf(src[k * H_ + row]);
    }
  }
}

// xp layout (R8-verified, matches swapped consumers):
//   x[t][batch m][col n] at xp[t*8192 + (m>>4)*4096 + (n>>2)*64 + (m&15)*4 + (n&3)]

// ---------------------------------------------------------------------------
// x0: swapped-operand form (R8-verified). Block = one time step t; 4 waves;
// wave w owns cols [w*64, +64) (nt=0..3); mt=0..1 batch halves.
// ---------------------------------------------------------------------------
__global__ __launch_bounds__(256, 2)
void x0_kernel(const int* __restrict__ ids, const float* __restrict__ emb,
               const u16* __restrict__ WiT0, const float* __restrict__ bh,
               float* __restrict__ xp){
  const int tid = threadIdx.x, w = tid >> 6, l = tid & 63;
  const int lr = l & 15, lh = l >> 4;
  const int t = blockIdx.x;

  b16x8 wA[4][8];
  #pragma unroll
  for (int nt = 0; nt < 4; ++nt){
    const int col = w * 64 + nt * 16 + lr;
    #pragma unroll
    for (int ks = 0; ks < 8; ++ks)
      wA[nt][ks] = *(const b16x8*)(WiT0 + (size_t)col * H_ + ks * 32 + lh * 8);
  }

  const int b0 = ids[t * B_ + lr];
  const int b1 = ids[t * B_ + 16 + lr];
  const float* er0 = emb + (size_t)b0 * H_;
  const float* er1 = emb + (size_t)b1 * H_;

  f32x4 acc[2][4];
  #pragma unroll
  for (int nt = 0; nt < 4; ++nt){
    f32x4 bs = *(const f32x4*)(bh + w * 64 + nt * 16 + lh * 4);
    acc[0][nt] = bs;
    acc[1][nt] = bs;
  }

  #pragma unroll
  for (int ks = 0; ks < 8; ++ks){
    b16x8 e[2];
    {
      f32x4 a0 = *(const f32x4*)(er0 + ks * 32 + lh * 8);
      f32x4 a1 = *(const f32x4*)(er0 + ks * 32 + lh * 8 + 4);
      f32x4 c0 = *(const f32x4*)(er1 + ks * 32 + lh * 8);
      f32x4 c1 = *(const f32x4*)(er1 + ks * 32 + lh * 8 + 4);
      #pragma unroll
      for (int i2 = 0; i2 < 4; ++i2){
        e[0][i2] = (short)f2bf(a0[i2]); e[0][4 + i2] = (short)f2bf(a1[i2]);
        e[1][i2] = (short)f2bf(c0[i2]); e[1][4 + i2] = (short)f2bf(c1[i2]);
      }
    }
    #pragma unroll
    for (int nt = 0; nt < 4; ++nt){
      acc[0][nt] = __builtin_amdgcn_mfma_f32_16x16x32_bf16(wA[nt][ks], e[0], acc[0][nt], 0, 0, 0);
      acc[1][nt] = __builtin_amdgcn_mfma_f32_16x16x32_bf16(wA[nt][ks], e[1], acc[1][nt], 0, 0, 0);
    }
  }
  #pragma unroll
  for (int mt = 0; mt < 2; ++mt)
    #pragma unroll
    for (int nt = 0; nt < 4; ++nt)
      *(f32x4*)(xp + (size_t)t * 8192 + mt * 4096 + w * 1024 + nt * 256 + lh * 64 + lr * 4)
          = acc[mt][nt];
}

// ---------------------------------------------------------------------------
// fused_rec16s: both layers, batch-split (2 blocks x 16 rows), 8 waves.
// Swapped-operand MFMA (R8-verified algebra at R7-verified geometry):
// A = weight frags (row = output col), B = h frags (col = batch row lr).
// Thread holds batch=lr, cols lh*4+rr (+nt*16+w*32) -> packed b64 h-writes.
// Skew schedule: step s -> h0[s], h1[s-1]; 1 barrier/step.
//   h0[u] in h0b[(u+1)&1]; h1[u] in h1b[(u+1)&1].
// LDS: byte(row,col) = row*512 + ((col*2) ^ ((row&7)<<4))
// ---------------------------------------------------------------------------
__global__ __launch_bounds__(512, 1)
void fused_rec16s(const u16* __restrict__ wt, const float* __restrict__ xp,
                  const float* __restrict__ bh,
                  u16* __restrict__ outseq, float* __restrict__ hid){
  __shared__ u16 h0b[2][16 * H_];                    // 2 x 8 KiB
  __shared__ u16 h1b[2][16 * H_];                    // 2 x 8 KiB
  const int tid = threadIdx.x, w = tid >> 6, l = tid & 63;
  const int lr = l & 15, lh = l >> 4;
  const int bid = blockIdx.x;

  const u16* whT0 = wt;
  const u16* wiT1 = wt + 65536;
  const u16* whT1 = wt + 131072;

  // persistent weight fragments [nt][ks] (A-role: row = output col)
  b16x8 wH0[2][8], wI1[2][8], wH1[2][8];
  #pragma unroll
  for (int nt = 0; nt < 2; ++nt){
    const int col = w * 32 + nt * 16 + lr;
    #pragma unroll
    for (int ks = 0; ks < 8; ++ks){
      wH0[nt][ks] = *(const b16x8*)(whT0 + (size_t)col * H_ + ks * 32 + lh * 8);
      wI1[nt][ks] = *(const b16x8*)(wiT1 + (size_t)col * H_ + ks * 32 + lh * 8);
      wH1[nt][ks] = *(const b16x8*)(whT1 + (size_t)col * H_ + ks * 32 + lh * 8);
    }
  }
  // layer-1 bias vectors (cols lh*4 .. +3 per nt)
  f32x4 bs1[2];
  #pragma unroll
  for (int nt = 0; nt < 2; ++nt)
    bs1[nt] = *(const f32x4*)(bh + H_ + w * 32 + nt * 16 + lh * 4);

  // B-fragment read offsets (row = lr, k = ks*32 + lh*8)
  int ra[8];
  #pragma unroll
  for (int ks = 0; ks < 8; ++ks)
    ra[ks] = lr * 512 + ((ks * 64 + lh * 16) ^ ((lr & 7) << 4));

  // packed h-write byte addrs (row = lr, col = w*32+nt*16+lh*4, 8 B)
  int wrh[2];
  #pragma unroll
  for (int nt = 0; nt < 2; ++nt)
    wrh[nt] = lr * 512 + ((w * 64 + nt * 32 + lh * 8) ^ ((lr & 7) << 4));

  // linear store-read (16 B/thread): row = tid>>5
  const int srow = tid >> 5, scolb = (tid & 31) * 16;
  const int sa = srow * 512 + (scolb ^ ((srow & 7) << 4));
  const size_t sgbase = (size_t)(bid * 16 + srow) * H_ + (tid & 31) * 8;

  const int xoff = bid * 4096 + w * 512 + lh * 64 + lr * 4;

  // zero h0[-1] (h0b[0]) and h1[-1] (h1b[0])
  { u32* z0 = (u32*)h0b[0];
    for (int i = tid; i < 2048; i += 512) z0[i] = 0;
    u32* z1 = (u32*)h1b[0];
    for (int i = tid; i < 2048; i += 512) z1[i] = 0; }

  f32x4 xc0, xc1, xn0, xn1;
  xc0 = *(const f32x4*)(xp + xoff);
  xc1 = *(const f32x4*)(xp + xoff + 256);
  __syncthreads();

#define PACKW(DST, ADDR, V0, V1, V2, V3)                                        \
  { u32x2 pk;                                                                   \
    pk[0] = (u32)f2bf(V0) | ((u32)f2bf(V1) << 16);                              \
    pk[1] = (u32)f2bf(V2) | ((u32)f2bf(V3) << 16);                              \
    *(u32x2*)((DST) + (ADDR)) = pk; }

#define STEP(PAR, S)                                                            \
  {                                                                             \
    const char* rb0 = (const char*)h0b[PAR];                                    \
    const char* rb1 = (const char*)h1b[1 - (PAR)];                              \
    if ((S) >= 2){                                                              \
      b16x8 v = *(const b16x8*)(rb1 + sa);                                      \
      *(b16x8*)(outseq + (size_t)((S) - 2) * 8192 + sgbase) = v;                \
    }                                                                           \
    f32x4 c0 = (f32x4){}, c1 = (f32x4){};                                       \
    f32x4 d0 = bs1[0], d1 = bs1[1];                                             \
    _Pragma("unroll")                                                           \
    for (int ks = 0; ks < 8; ++ks){                                             \
      b16x8 a = *(const b16x8*)(rb0 + ra[ks]);                                  \
      c0 = __builtin_amdgcn_mfma_f32_16x16x32_bf16(wH0[0][ks], a, c0, 0, 0, 0); \
      c1 = __builtin_amdgcn_mfma_f32_16x16x32_bf16(wH0[1][ks], a, c1, 0, 0, 0); \
      d0 = __builtin_amdgcn_mfma_f32_16x16x32_bf16(wI1[0][ks], a, d0, 0, 0, 0); \
      d1 = __builtin_amdgcn_mfma_f32_16x16x32_bf16(wI1[1][ks], a, d1, 0, 0, 0); \
    }                                                                           \
    { const float* pn = xp + (size_t)(((S) < 255) ? (S) + 1 : 255) * 8192 + xoff; \
      xn0 = *(const f32x4*)(pn);                                                \
      xn1 = *(const f32x4*)(pn + 256); }                                        \
    { char* wb0 = (char*)h0b[1 - (PAR)];                                        \
      PACKW(wb0, wrh[0], sigm_fast(c0[0] + xc0[0]), sigm_fast(c0[1] + xc0[1]),  \
                         sigm_fast(c0[2] + xc0[2]), sigm_fast(c0[3] + xc0[3]))  \
      PACKW(wb0, wrh[1], sigm_fast(c1[0] + xc1[0]), sigm_fast(c1[1] + xc1[1]),  \
                         sigm_fast(c1[2] + xc1[2]), sigm_fast(c1[3] + xc1[3]))  \
    }                                                                           \
    if ((S) >= 1){                                                              \
      _Pragma("unroll")                                                         \
      for (int ks = 0; ks < 8; ++ks){                                           \
        b16x8 a = *(const b16x8*)(rb1 + ra[ks]);                                \
        d0 = __builtin_amdgcn_mfma_f32_16x16x32_bf16(wH1[0][ks], a, d0, 0, 0, 0); \
        d1 = __builtin_amdgcn_mfma_f32_16x16x32_bf16(wH1[1][ks], a, d1, 0, 0, 0); \
      }                                                                         \
      char* wb1 = (char*)h1b[PAR];                                              \
      PACKW(wb1, wrh[0], sigm_fast(d0[0]), sigm_fast(d0[1]),                    \
                         sigm_fast(d0[2]), sigm_fast(d0[3]))                    \
      PACKW(wb1, wrh[1], sigm_fast(d1[0]), sigm_fast(d1[1]),                    \
                         sigm_fast(d1[2]), sigm_fast(d1[3]))                    \
    }                                                                           \
    xc0 = xn0; xc1 = xn1;                                                       \
    __syncthreads();                                                            \
  }

  for (int s2 = 0; s2 < 128; ++s2){
    const int s = s2 * 2;
    STEP(0, s)
    STEP(1, s + 1)
  }
#undef STEP

  // epilogue: h0[255] in h0b[0]; h1[254] in h1b[1]; compute h1[255]
  {
    const char* rb0 = (const char*)h0b[0];
    const char* rb1 = (const char*)h1b[1];
    { b16x8 v = *(const b16x8*)(rb1 + sa);
      *(b16x8*)(outseq + (size_t)254 * 8192 + sgbase) = v; }

    f32x4 d0 = bs1[0], d1 = bs1[1];
    #pragma unroll
    for (int ks = 0; ks < 8; ++ks){
      b16x8 a0 = *(const b16x8*)(rb0 + ra[ks]);
      b16x8 a1 = *(const b16x8*)(rb1 + ra[ks]);
      d0 = __builtin_amdgcn_mfma_f32_16x16x32_bf16(wI1[0][ks], a0, d0, 0, 0, 0);
      d1 = __builtin_amdgcn_mfma_f32_16x16x32_bf16(wI1[1][ks], a0, d1, 0, 0, 0);
      d0 = __builtin_amdgcn_mfma_f32_16x16x32_bf16(wH1[0][ks], a1, d0, 0, 0, 0);
      d1 = __builtin_amdgcn_mfma_f32_16x16x32_bf16(wH1[1][ks], a1, d1, 0, 0, 0);
    }
    { char* wb1 = (char*)h1b[0];
      PACKW(wb1, wrh[0], sigm_fast(d0[0]), sigm_fast(d0[1]),
                         sigm_fast(d0[2]), sigm_fast(d0[3]))
      PACKW(wb1, wrh[1], sigm_fast(d1[0]), sigm_fast(d1[1]),
                         sigm_fast(d1[2]), sigm_fast(d1[3]))
    }
    __syncthreads();

    b16x8 h1v = *(const b16x8*)((const char*)h1b[0] + sa);
    b16x8 h0v = *(const b16x8*)((const char*)h0b[0] + sa);
    *(b16x8*)(outseq + (size_t)255 * 8192 + sgbase) = h1v;
    float* hd0 = hid + sgbase;
    float* hd1 = hid + 8192 + sgbase;
    #pragma unroll
    for (int j = 0; j < 8; ++j){
      hd0[j] = bf2f(h0v[j]);
      hd1[j] = bf2f(h1v[j]);
    }
  }
#undef PACKW
}

// ---------------------------------------------------------------------------
// decoder (R4-verified 256x256/BK=64 structure + nontemporal stores)
// ---------------------------------------------------------------------------
__global__ __launch_bounds__(512, 1)
void dec_kernel(const u16* __restrict__ A, const u16* __restrict__ Bw,
                const float* __restrict__ decB, float* __restrict__ out){
  __shared__ u16 sA[2][256 * 64];
  __shared__ u16 sB[2][256 * 64];
  const int tid = threadIdx.x, w = tid >> 6, l = tid & 63;
  const int la = l & 31, hi = l >> 5;
  const int wm = w >> 2, wn = w & 3;

  const int bid = blockIdx.x;
  const int sb  = (bid & 7) * 500 + (bid >> 3);
  const int mb  = sb & 31;
  const int nb  = sb >> 5;

  const int srow = tid >> 3;
  const int sc   = tid & 7;
  const int scx  = sc ^ (srow & 7);
  const size_t gA = ((size_t)(mb * 256 + srow)) * H_ + sc * 8;
  const size_t gB = ((size_t)(nb * 256 + srow)) * H_ + sc * 8;
  const int    sl = srow * 128 + scx * 16;

  b16x8 rA[4], rB[4];
#define GLOADS(KK)                                                              \
  { _Pragma("unroll")                                                           \
    for (int s = 0; s < 4; ++s){                                                \
      rA[s] = *(const b16x8*)(A  + gA + (size_t)s * 64 * H_ + (KK) * 64);       \
      rB[s] = *(const b16x8*)(Bw + gB + (size_t)s * 64 * H_ + (KK) * 64);       \
    } }
#define DSWRITE(BUF)                                                            \
  { _Pragma("unroll")                                                           \
    for (int s = 0; s < 4; ++s){                                                \
      *(b16x8*)((char*)sA[BUF] + s * 8192 + sl) = rA[s];                        \
      *(b16x8*)((char*)sB[BUF] + s * 8192 + sl) = rB[s];                        \
    } }

  const int aRow = wm * 128 + la;
  const int bRow = wn * 64 + la;
  int fOff[4];
  #pragma unroll
  for (int ks = 0; ks < 4; ++ks)
    fOff[ks] = ((ks * 32 + hi * 16) ^ ((la & 7) << 4));

  f32x16 acc[4][2];
  #pragma unroll
  for (int mt = 0; mt < 4; ++mt)
    #pragma unroll
    for (int nt = 0; nt < 2; ++nt)
      acc[mt][nt] = (f32x16){};

  GLOADS(0);
  #pragma unroll
  for (int kk = 0; kk < 4; ++kk){
    DSWRITE(kk & 1);
    if (kk < 3) GLOADS(kk + 1);
    __syncthreads();
    const char* bufA = (const char*)sA[kk & 1];
    const char* bufB = (const char*)sB[kk & 1];
    #pragma unroll
    for (int ks = 0; ks < 4; ++ks){
      b16x8 aF[4], bF[2];
      #pragma unroll
      for (int mt = 0; mt < 4; ++mt)
        aF[mt] = *(const b16x8*)(bufA + (aRow + mt * 32) * 128 + fOff[ks]);
      #pragma unroll
      for (int nt = 0; nt < 2; ++nt)
        bF[nt] = *(const b16x8*)(bufB + (bRow + nt * 32) * 128 + fOff[ks]);
      #pragma unroll
      for (int mt = 0; mt < 4; ++mt)
        #pragma unroll
        for (int nt = 0; nt < 2; ++nt)
          acc[mt][nt] = __builtin_amdgcn_mfma_f32_32x32x16_bf16(aF[mt], bF[nt], acc[mt][nt], 0, 0, 0);
    }
    __syncthreads();
  }
#undef GLOADS
#undef DSWRITE

  #pragma unroll
  for (int nt = 0; nt < 2; ++nt){
    const int colg = nb * 256 + wn * 64 + nt * 32 + la;
    const float bias = decB[colg];
    #pragma unroll
    for (int mt = 0; mt < 4; ++mt){
      const int rowb = mb * 256 + wm * 128 + mt * 32 + hi * 4;
      #pragma unroll
      for (int r = 0; r < 16; ++r){
        const int rowg = rowb + (r & 3) + 8 * (r >> 2);
        __builtin_nontemporal_store(acc[mt][nt][r] + bias,
                                    &out[(size_t)rowg * V_ + colg]);
      }
    }
  }
}

// ---------------------------------------------------------------------------
extern "C" void kernel_launch(void* const* d_in, const int* in_sizes, int n_in,
                              void* d_out, int out_size, void* d_ws, size_t ws_size,
                              hipStream_t stream){
  const int*   ids  = (const int*)  d_in[0];
  const float* emb  = (const float*)d_in[1];
  const float* Wi   = (const float*)d_in[2];
  const float* Wh   = (const float*)d_in[3];
  const float* bh   = (const float*)d_in[4];
  const float* decW = (const float*)d_in[5];
  const float* decB = (const float*)d_in[6];
  float* out = (float*)d_out;

  char* ws = (char*)d_ws;
  u16*  decWb  = (u16*)(ws);                       // 16,384,000 B
  u16*  wt     = (u16*)(ws + 16384000);            //    524,288 B
  u16*  outseq = (u16*)(ws + 16908288);            //  4,194,304 B
  float* xp    = (float*)(ws + 21102592);          //  8,388,608 B

  float* hid = out + (size_t)T_ * B_ * V_;         // [L][B][H] fp32 tail of d_out

  prep_kernel<<<2048, 256, 0, stream>>>(Wi, Wh, decW, decWb, wt);
  x0_kernel<<<256, 256, 0, stream>>>(ids, emb, wt + 3 * H_ * H_, bh, xp);
  fused_rec16s<<<2, 512, 0, stream>>>(wt, xp, bh, outseq, hid);
  dec_kernel<<<4000, 512, 0, stream>>>(outseq, decWb, decB, out);
}

// Round 11
// 453.602 us; speedup vs baseline: 2.4780x; 1.3638x over previous
//
#include <hip/hip_runtime.h>

typedef unsigned short u16;
typedef unsigned int   u32;
typedef unsigned long long u64;
typedef __attribute__((ext_vector_type(2)))  u32  u32x2;
typedef __attribute__((ext_vector_type(4)))  float f32x4;
typedef __attribute__((ext_vector_type(16))) float f32x16;
typedef __attribute__((ext_vector_type(8)))  short b16x8;

#define T_ 256
#define B_ 32
#define V_ 32000
#define H_ 256

// fp32 -> bf16 round-to-nearest-even
__device__ __forceinline__ u16 f2bf(float f){
  union { float fv; u32 uv; } v; v.fv = f;
  return (u16)((v.uv + 0x7FFFu + ((v.uv >> 16) & 1u)) >> 16);
}
__device__ __forceinline__ float bf2f(short x){
  union { float fv; u32 uv; } c; c.uv = ((u32)(u16)x) << 16; return c.fv;
}
__device__ __forceinline__ float sigm_fast(float z){
  return __builtin_amdgcn_rcpf(1.0f + __builtin_amdgcn_exp2f(z * -1.44269504f));
}
// 16B agent-scope (cross-XCD coherent) load/store as 2x u64 atomics
__device__ __forceinline__ b16x8 ald16(const u16* p){
  union { u64 q[2]; b16x8 v; } u;
  const u64* q = (const u64*)p;
  u.q[0] = __hip_atomic_load(q,     __ATOMIC_RELAXED, __HIP_MEMORY_SCOPE_AGENT);
  u.q[1] = __hip_atomic_load(q + 1, __ATOMIC_RELAXED, __HIP_MEMORY_SCOPE_AGENT);
  return u.v;
}
__device__ __forceinline__ void ast16(u16* p, b16x8 v){
  union { u64 q[2]; b16x8 v; } u; u.v = v;
  u64* q = (u64*)p;
  __hip_atomic_store(q,     u.q[0], __ATOMIC_RELAXED, __HIP_MEMORY_SCOPE_AGENT);
  __hip_atomic_store(q + 1, u.q[1], __ATOMIC_RELAXED, __HIP_MEMORY_SCOPE_AGENT);
}

// ---------------------------------------------------------------------------
// prep: decW -> bf16 ; W^T bf16 copies (WhT0, WiT1, WhT1, WiT0) ; flag reset
// ---------------------------------------------------------------------------
__global__ __launch_bounds__(256)
void prep_kernel(const float* __restrict__ Wi, const float* __restrict__ Wh,
                 const float* __restrict__ decW,
                 u16* __restrict__ decWb, u16* __restrict__ wt,
                 u32* __restrict__ flags){
  if (blockIdx.x == 0 && threadIdx.x == 0){ flags[0] = 0; flags[1] = 0; }
  const int NDEC = V_ * H_;
  const int NWT  = 4 * H_ * H_;
  const int total = NDEC + NWT;
  for (int i = blockIdx.x * blockDim.x + threadIdx.x; i < total;
       i += gridDim.x * blockDim.x){
    if (i < NDEC){
      decWb[i] = f2bf(decW[i]);
    } else {
      int j = i - NDEC;
      int m = j >> 16;
      int r = j & 65535;
      int row = r >> 8;
      int k   = r & 255;
      const float* src = (m == 0) ? Wh
                       : (m == 1) ? (Wi + H_ * H_)
                       : (m == 2) ? (Wh + H_ * H_)
                       :            Wi;
      wt[j] = f2bf(src[k * H_ + row]);
    }
  }
}

// xp layout (R8/R10-verified, matches swapped consumers):
//   x[t][batch m][col n] at xp[t*8192 + (m>>4)*4096 + (n>>2)*64 + (m&15)*4 + (n&3)]

// ---------------------------------------------------------------------------
// x0: swapped-operand form (R8/R10-verified). Block = one step t; 4 waves.
// ---------------------------------------------------------------------------
__global__ __launch_bounds__(256, 2)
void x0_kernel(const int* __restrict__ ids, const float* __restrict__ emb,
               const u16* __restrict__ WiT0, const float* __restrict__ bh,
               float* __restrict__ xp){
  const int tid = threadIdx.x, w = tid >> 6, l = tid & 63;
  const int lr = l & 15, lh = l >> 4;
  const int t = blockIdx.x;

  b16x8 wA[4][8];
  #pragma unroll
  for (int nt = 0; nt < 4; ++nt){
    const int col = w * 64 + nt * 16 + lr;
    #pragma unroll
    for (int ks = 0; ks < 8; ++ks)
      wA[nt][ks] = *(const b16x8*)(WiT0 + (size_t)col * H_ + ks * 32 + lh * 8);
  }

  const int b0 = ids[t * B_ + lr];
  const int b1 = ids[t * B_ + 16 + lr];
  const float* er0 = emb + (size_t)b0 * H_;
  const float* er1 = emb + (size_t)b1 * H_;

  f32x4 acc[2][4];
  #pragma unroll
  for (int nt = 0; nt < 4; ++nt){
    f32x4 bs = *(const f32x4*)(bh + w * 64 + nt * 16 + lh * 4);
    acc[0][nt] = bs;
    acc[1][nt] = bs;
  }

  #pragma unroll
  for (int ks = 0; ks < 8; ++ks){
    b16x8 e[2];
    {
      f32x4 a0 = *(const f32x4*)(er0 + ks * 32 + lh * 8);
      f32x4 a1 = *(const f32x4*)(er0 + ks * 32 + lh * 8 + 4);
      f32x4 c0 = *(const f32x4*)(er1 + ks * 32 + lh * 8);
      f32x4 c1 = *(const f32x4*)(er1 + ks * 32 + lh * 8 + 4);
      #pragma unroll
      for (int i2 = 0; i2 < 4; ++i2){
        e[0][i2] = (short)f2bf(a0[i2]); e[0][4 + i2] = (short)f2bf(a1[i2]);
        e[1][i2] = (short)f2bf(c0[i2]); e[1][4 + i2] = (short)f2bf(c1[i2]);
      }
    }
    #pragma unroll
    for (int nt = 0; nt < 4; ++nt){
      acc[0][nt] = __builtin_amdgcn_mfma_f32_16x16x32_bf16(wA[nt][ks], e[0], acc[0][nt], 0, 0, 0);
      acc[1][nt] = __builtin_amdgcn_mfma_f32_16x16x32_bf16(wA[nt][ks], e[1], acc[1][nt], 0, 0, 0);
    }
  }
  #pragma unroll
  for (int mt = 0; mt < 2; ++mt)
    #pragma unroll
    for (int nt = 0; nt < 4; ++nt)
      *(f32x4*)(xp + (size_t)t * 8192 + mt * 4096 + w * 1024 + nt * 256 + lh * 64 + lr * 4)
          = acc[mt][nt];
}

// ---------------------------------------------------------------------------
// mega: blocks 0-1 = rec (R10-verified fused_rec16s + sc1 outseq stores +
// progress flags); blocks 2..4001 = dec (R10-verified 256x256/BK=64 + spin +
// sc1 outseq staging loads). mb-major dec order so resident spinners are the
// soonest-satisfiable tiles.
// ---------------------------------------------------------------------------
__global__ __launch_bounds__(512, 1)
void mega_kernel(const u16* __restrict__ wt, const float* __restrict__ xp,
                 const float* __restrict__ bh,
                 u16* __restrict__ outseq, float* __restrict__ hid,
                 const u16* __restrict__ decWb, const float* __restrict__ decB,
                 float* __restrict__ out, u32* __restrict__ flags){
  __shared__ u16 smu[65536];                        // 128 KiB union
  char* smem = (char*)smu;
  const int tid = threadIdx.x, w = tid >> 6, l = tid & 63;
  const int bid = blockIdx.x;

  if (bid < 2){
    // =============== rec: both layers, batch rows [bid*16, +16) ===========
    // LDS: h0 bufs at smem + {0,8192}; h1 bufs at smem + 16384 + {0,8192}
    const int lr = l & 15, lh = l >> 4;

    const u16* whT0 = wt;
    const u16* wiT1 = wt + 65536;
    const u16* whT1 = wt + 131072;

    b16x8 wH0[2][8], wI1[2][8], wH1[2][8];
    #pragma unroll
    for (int nt = 0; nt < 2; ++nt){
      const int col = w * 32 + nt * 16 + lr;
      #pragma unroll
      for (int ks = 0; ks < 8; ++ks){
        wH0[nt][ks] = *(const b16x8*)(whT0 + (size_t)col * H_ + ks * 32 + lh * 8);
        wI1[nt][ks] = *(const b16x8*)(wiT1 + (size_t)col * H_ + ks * 32 + lh * 8);
        wH1[nt][ks] = *(const b16x8*)(whT1 + (size_t)col * H_ + ks * 32 + lh * 8);
      }
    }
    f32x4 bs1[2];
    #pragma unroll
    for (int nt = 0; nt < 2; ++nt)
      bs1[nt] = *(const f32x4*)(bh + H_ + w * 32 + nt * 16 + lh * 4);

    int ra[8];
    #pragma unroll
    for (int ks = 0; ks < 8; ++ks)
      ra[ks] = lr * 512 + ((ks * 64 + lh * 16) ^ ((lr & 7) << 4));

    int wrh[2];
    #pragma unroll
    for (int nt = 0; nt < 2; ++nt)
      wrh[nt] = lr * 512 + ((w * 64 + nt * 32 + lh * 8) ^ ((lr & 7) << 4));

    const int srow = tid >> 5, scolb = (tid & 31) * 16;
    const int sa = srow * 512 + (scolb ^ ((srow & 7) << 4));
    const size_t sgbase = (size_t)(bid * 16 + srow) * H_ + (tid & 31) * 8;

    const int xoff = bid * 4096 + w * 512 + lh * 64 + lr * 4;

    { u32* z = (u32*)smem;
      for (int i = tid; i < 8192; i += 512) z[i] = 0; }   // h0[-1], h1[-1] = 0

    f32x4 xc0, xc1, xn0, xn1;
    xc0 = *(const f32x4*)(xp + xoff);
    xc1 = *(const f32x4*)(xp + xoff + 256);
    __syncthreads();

#define PACKW(DST, ADDR, V0, V1, V2, V3)                                        \
  { u32x2 pk;                                                                   \
    pk[0] = (u32)f2bf(V0) | ((u32)f2bf(V1) << 16);                              \
    pk[1] = (u32)f2bf(V2) | ((u32)f2bf(V3) << 16);                              \
    *(u32x2*)((DST) + (ADDR)) = pk; }

#define STEP(PAR, S)                                                            \
  {                                                                             \
    const char* rb0 = smem + (PAR) * 8192;                                      \
    const char* rb1 = smem + 16384 + (1 - (PAR)) * 8192;                        \
    if ((S) >= 2){                                                              \
      b16x8 v = *(const b16x8*)(rb1 + sa);                                      \
      ast16(outseq + (size_t)((S) - 2) * 8192 + sgbase, v);                     \
    }                                                                           \
    f32x4 c0 = (f32x4){}, c1 = (f32x4){};                                       \
    f32x4 d0 = bs1[0], d1 = bs1[1];                                             \
    _Pragma("unroll")                                                           \
    for (int ks = 0; ks < 8; ++ks){                                             \
      b16x8 a = *(const b16x8*)(rb0 + ra[ks]);                                  \
      c0 = __builtin_amdgcn_mfma_f32_16x16x32_bf16(wH0[0][ks], a, c0, 0, 0, 0); \
      c1 = __builtin_amdgcn_mfma_f32_16x16x32_bf16(wH0[1][ks], a, c1, 0, 0, 0); \
      d0 = __builtin_amdgcn_mfma_f32_16x16x32_bf16(wI1[0][ks], a, d0, 0, 0, 0); \
      d1 = __builtin_amdgcn_mfma_f32_16x16x32_bf16(wI1[1][ks], a, d1, 0, 0, 0); \
    }                                                                           \
    { const float* pn = xp + (size_t)(((S) < 255) ? (S) + 1 : 255) * 8192 + xoff; \
      xn0 = *(const f32x4*)(pn);                                                \
      xn1 = *(const f32x4*)(pn + 256); }                                        \
    { char* wb0 = smem + (1 - (PAR)) * 8192;                                    \
      PACKW(wb0, wrh[0], sigm_fast(c0[0] + xc0[0]), sigm_fast(c0[1] + xc0[1]),  \
                         sigm_fast(c0[2] + xc0[2]), sigm_fast(c0[3] + xc0[3]))  \
      PACKW(wb0, wrh[1], sigm_fast(c1[0] + xc1[0]), sigm_fast(c1[1] + xc1[1]),  \
                         sigm_fast(c1[2] + xc1[2]), sigm_fast(c1[3] + xc1[3]))  \
    }                                                                           \
    if ((S) >= 1){                                                              \
      _Pragma("unroll")                                                         \
      for (int ks = 0; ks < 8; ++ks){                                           \
        b16x8 a = *(const b16x8*)(rb1 + ra[ks]);                                \
        d0 = __builtin_amdgcn_mfma_f32_16x16x32_bf16(wH1[0][ks], a, d0, 0, 0, 0); \
        d1 = __builtin_amdgcn_mfma_f32_16x16x32_bf16(wH1[1][ks], a, d1, 0, 0, 0); \
      }                                                                         \
      char* wb1 = smem + 16384 + (PAR) * 8192;                                  \
      PACKW(wb1, wrh[0], sigm_fast(d0[0]), sigm_fast(d0[1]),                    \
                         sigm_fast(d0[2]), sigm_fast(d0[3]))                    \
      PACKW(wb1, wrh[1], sigm_fast(d1[0]), sigm_fast(d1[1]),                    \
                         sigm_fast(d1[2]), sigm_fast(d1[3]))                    \
    }                                                                           \
    xc0 = xn0; xc1 = xn1;                                                       \
    __syncthreads();                                                            \
  }

    for (int s2 = 0; s2 < 128; ++s2){
      const int s = s2 * 2;
      STEP(0, s)
      STEP(1, s + 1)
      if (((s2 & 7) == 7) && tid == 0)   // after barrier: steps <= 2*s2+1 stored
        __hip_atomic_store(&flags[bid], (u32)(s2 * 2), __ATOMIC_RELEASE,
                           __HIP_MEMORY_SCOPE_AGENT);
    }
#undef STEP

    // epilogue: h0[255] in h0 buf0; h1[254] in h1 buf1; compute h1[255]
    {
      const char* rb0 = smem;
      const char* rb1 = smem + 16384 + 8192;
      { b16x8 v = *(const b16x8*)(rb1 + sa);
        ast16(outseq + (size_t)254 * 8192 + sgbase, v); }

      f32x4 d0 = bs1[0], d1 = bs1[1];
      #pragma unroll
      for (int ks = 0; ks < 8; ++ks){
        b16x8 a0 = *(const b16x8*)(rb0 + ra[ks]);
        b16x8 a1 = *(const b16x8*)(rb1 + ra[ks]);
        d0 = __builtin_amdgcn_mfma_f32_16x16x32_bf16(wI1[0][ks], a0, d0, 0, 0, 0);
        d1 = __builtin_amdgcn_mfma_f32_16x16x32_bf16(wI1[1][ks], a0, d1, 0, 0, 0);
        d0 = __builtin_amdgcn_mfma_f32_16x16x32_bf16(wH1[0][ks], a1, d0, 0, 0, 0);
        d1 = __builtin_amdgcn_mfma_f32_16x16x32_bf16(wH1[1][ks], a1, d1, 0, 0, 0);
      }
      { char* wb1 = smem + 16384;
        PACKW(wb1, wrh[0], sigm_fast(d0[0]), sigm_fast(d0[1]),
                           sigm_fast(d0[2]), sigm_fast(d0[3]))
        PACKW(wb1, wrh[1], sigm_fast(d1[0]), sigm_fast(d1[1]),
                           sigm_fast(d1[2]), sigm_fast(d1[3]))
      }
      __syncthreads();

      b16x8 h1v = *(const b16x8*)(smem + 16384 + sa);
      b16x8 h0v = *(const b16x8*)(smem + sa);
      ast16(outseq + (size_t)255 * 8192 + sgbase, h1v);
      float* hd0 = hid + sgbase;
      float* hd1 = hid + 8192 + sgbase;
      #pragma unroll
      for (int j = 0; j < 8; ++j){
        hd0[j] = bf2f(h0v[j]);
        hd1[j] = bf2f(h1v[j]);
      }
      __syncthreads();
      if (tid == 0)
        __hip_atomic_store(&flags[bid], 256u, __ATOMIC_RELEASE,
                           __HIP_MEMORY_SCOPE_AGENT);
    }
#undef PACKW
  } else {
    // =============== dec: decoded = outseq @ decW^T + decB ================
    // LDS: sA bufs at smem + {0,32768}; sB bufs at smem + 65536 + {0,32768}
    const int la = l & 31, hi = l >> 5;
    const int wm = w >> 2, wn = w & 3;

    const int idx = bid - 2;
    const int mb  = idx / 125;                      // mb-major dispatch order
    const int nb  = idx - mb * 125;

    // wait until outseq rows [mb*256, +256) (steps [mb*8, mb*8+8)) published
    if (tid == 0){
      const u32 need = (u32)(mb * 8 + 8);
      const u64* fl = (const u64*)flags;
      for (;;){
        u64 ff = __hip_atomic_load(fl, __ATOMIC_RELAXED, __HIP_MEMORY_SCOPE_AGENT);
        if ((u32)ff >= need && (u32)(ff >> 32) >= need) break;
        __builtin_amdgcn_s_sleep(32);
      }
    }
    __syncthreads();

    const int srow = tid >> 3;
    const int sc   = tid & 7;
    const int scx  = sc ^ (srow & 7);
    const size_t gA = ((size_t)(mb * 256 + srow)) * H_ + sc * 8;
    const size_t gB = ((size_t)(nb * 256 + srow)) * H_ + sc * 8;
    const int    sl = srow * 128 + scx * 16;

    b16x8 rA[4], rB[4];
#define GLOADS(KK)                                                              \
  { _Pragma("unroll")                                                           \
    for (int s5 = 0; s5 < 4; ++s5){                                             \
      rA[s5] = ald16(outseq + gA + (size_t)s5 * 64 * H_ + (KK) * 64);           \
      rB[s5] = *(const b16x8*)(decWb + gB + (size_t)s5 * 64 * H_ + (KK) * 64);  \
    } }
#define DSWRITE(BUF)                                                            \
  { _Pragma("unroll")                                                           \
    for (int s5 = 0; s5 < 4; ++s5){                                             \
      *(b16x8*)(smem + (BUF) * 32768 + s5 * 8192 + sl)         = rA[s5];        \
      *(b16x8*)(smem + 65536 + (BUF) * 32768 + s5 * 8192 + sl) = rB[s5];        \
    } }

    const int aRow = wm * 128 + la;
    const int bRow = wn * 64 + la;
    int fOff[4];
    #pragma unroll
    for (int ks = 0; ks < 4; ++ks)
      fOff[ks] = ((ks * 32 + hi * 16) ^ ((la & 7) << 4));

    f32x16 acc[4][2];
    #pragma unroll
    for (int mt = 0; mt < 4; ++mt)
      #pragma unroll
      for (int nt = 0; nt < 2; ++nt)
        acc[mt][nt] = (f32x16){};

    GLOADS(0);
    #pragma unroll
    for (int kk = 0; kk < 4; ++kk){
      DSWRITE(kk & 1);
      if (kk < 3) GLOADS(kk + 1);
      __syncthreads();
      const char* bufA = smem + (kk & 1) * 32768;
      const char* bufB = smem + 65536 + (kk & 1) * 32768;
      #pragma unroll
      for (int ks = 0; ks < 4; ++ks){
        b16x8 aF[4], bF[2];
        #pragma unroll
        for (int mt = 0; mt < 4; ++mt)
          aF[mt] = *(const b16x8*)(bufA + (aRow + mt * 32) * 128 + fOff[ks]);
        #pragma unroll
        for (int nt = 0; nt < 2; ++nt)
          bF[nt] = *(const b16x8*)(bufB + (bRow + nt * 32) * 128 + fOff[ks]);
        #pragma unroll
        for (int mt = 0; mt < 4; ++mt)
          #pragma unroll
          for (int nt = 0; nt < 2; ++nt)
            acc[mt][nt] = __builtin_amdgcn_mfma_f32_32x32x16_bf16(aF[mt], bF[nt], acc[mt][nt], 0, 0, 0);
      }
      __syncthreads();
    }
#undef GLOADS
#undef DSWRITE

    #pragma unroll
    for (int nt = 0; nt < 2; ++nt){
      const int colg = nb * 256 + wn * 64 + nt * 32 + la;
      const float bias = decB[colg];
      #pragma unroll
      for (int mt = 0; mt < 4; ++mt){
        const int rowb = mb * 256 + wm * 128 + mt * 32 + hi * 4;
        #pragma unroll
        for (int r = 0; r < 16; ++r){
          const int rowg = rowb + (r & 3) + 8 * (r >> 2);
          __builtin_nontemporal_store(acc[mt][nt][r] + bias,
                                      &out[(size_t)rowg * V_ + colg]);
        }
      }
    }
  }
}

// ---------------------------------------------------------------------------
extern "C" void kernel_launch(void* const* d_in, const int* in_sizes, int n_in,
                              void* d_out, int out_size, void* d_ws, size_t ws_size,
                              hipStream_t stream){
  const int*   ids  = (const int*)  d_in[0];
  const float* emb  = (const float*)d_in[1];
  const float* Wi   = (const float*)d_in[2];
  const float* Wh   = (const float*)d_in[3];
  const float* bh   = (const float*)d_in[4];
  const float* decW = (const float*)d_in[5];
  const float* decB = (const float*)d_in[6];
  float* out = (float*)d_out;

  char* ws = (char*)d_ws;
  u16*  decWb  = (u16*)(ws);                       // 16,384,000 B
  u16*  wt     = (u16*)(ws + 16384000);            //    524,288 B
  u16*  outseq = (u16*)(ws + 16908288);            //  4,194,304 B
  float* xp    = (float*)(ws + 21102592);          //  8,388,608 B
  u32*  flags  = (u32*)(ws + 29491200);            //          8 B

  float* hid = out + (size_t)T_ * B_ * V_;         // [L][B][H] fp32 tail of d_out

  prep_kernel<<<2048, 256, 0, stream>>>(Wi, Wh, decW, decWb, wt, flags);
  x0_kernel<<<256, 256, 0, stream>>>(ids, emb, wt + 3 * H_ * H_, bh, xp);
  mega_kernel<<<4002, 512, 0, stream>>>(wt, xp, bh, outseq, hid,
                                        decWb, decB, out, flags);
}